// Round 3
// baseline (19152.995 us; speedup 1.0000x reference)
//
#include <hip/hip_runtime.h>
#include <math.h>
#include <float.h>

#define BN   2
#define NPTS 16384
#define MPTS 4096
#define KGN  32
#define CIN  64
#define CLN  64

// ---------- exact fp32 helpers (no FMA contraction; must match np fp32) ----------
__device__ __forceinline__ float exadd(float a, float b) {
#pragma clang fp contract(off)
    float r = a + b; return r;
}
__device__ __forceinline__ float exsub(float a, float b) {
#pragma clang fp contract(off)
    float r = a - b; return r;
}
__device__ __forceinline__ float exmul(float a, float b) {
#pragma clang fp contract(off)
    float r = a * b; return r;
}

__device__ __forceinline__ float wave_sum64(float v) {
#pragma unroll
    for (int off = 1; off < 64; off <<= 1) v += __shfl_xor(v, off);
    return v;
}

// =====================================================================
// K0: pack points as float4(x, y, z, ||p||^2) once. sb order matches
// jnp.sum(b*b,-1): ((x*x + y*y) + z*z), contract off. Values verbatim.
// =====================================================================
__global__ __launch_bounds__(256) void prep_kernel(const float* __restrict__ xyz,
                                                   float4* __restrict__ pts4) {
    const int i = blockIdx.x * 256 + threadIdx.x;   // 0 .. BN*NPTS-1
    const float x = xyz[3 * i + 0];
    const float y = xyz[3 * i + 1];
    const float z = xyz[3 * i + 2];
    const float sb = exadd(exadd(exmul(x, x), exmul(y, y)), exmul(z, z));
    pts4[i] = make_float4(x, y, z, sb);
}

// =====================================================================
// K1: FPS — R1's PASSING kernel verbatim (scalar exact math, 3-barrier
// reduce, t==0 serial second level, same tie-breaks). Only changes:
// __launch_bounds__(1024,4) => 128-VGPR budget (no scratch spill), and
// float4 input reads (bit-identical values).
// =====================================================================
__global__ __launch_bounds__(1024, 4) void fps_kernel(const float4* __restrict__ P4,
                                                      int* __restrict__ out_idx) {
    const int b = blockIdx.x;
    const int t = threadIdx.x;
    const float4* P = P4 + (size_t)b * NPTS;

    float px[16], py[16], pz[16], dist[16];
#pragma unroll
    for (int i = 0; i < 16; ++i) {
        float4 a = P[t * 16 + i];
        px[i] = a.x;
        py[i] = a.y;
        pz[i] = a.z;
        dist[i] = 1e10f;
    }

    __shared__ float sc[3];
    __shared__ int   sfar;
    __shared__ unsigned long long swave[16];
    __shared__ unsigned long long swin;

    if (t == 0) { sc[0] = px[0]; sc[1] = py[0]; sc[2] = pz[0]; sfar = 0; }
    __syncthreads();

    for (int m = 0; m < MPTS; ++m) {
        float cx = sc[0], cy = sc[1], cz = sc[2];
        if (t == 0) out_idx[b * MPTS + m] = sfar;

        float lmax = -1.0f;
#pragma unroll
        for (int i = 0; i < 16; ++i) {
            float dx = exsub(px[i], cx);
            float dy = exsub(py[i], cy);
            float dz = exsub(pz[i], cz);
            float d  = exadd(exadd(exmul(dx, dx), exmul(dy, dy)), exmul(dz, dz));
            float nd = fminf(dist[i], d);
            dist[i] = nd;
            lmax = fmaxf(lmax, nd);
        }
        // pack: value bits in hi 32 (dist >= 0 so monotone), ~tid in lo 32 -> max picks min tid on ties
        unsigned long long pk =
            ((unsigned long long)__float_as_uint(lmax) << 32) |
            (unsigned long long)(0xFFFFFFFFu - (unsigned)t);
#pragma unroll
        for (int off = 32; off > 0; off >>= 1) {
            unsigned long long o = __shfl_xor(pk, off);
            pk = (o > pk) ? o : pk;
        }
        if ((t & 63) == 0) swave[t >> 6] = pk;
        __syncthreads();
        if (t == 0) {
            unsigned long long w = swave[0];
#pragma unroll
            for (int i = 1; i < 16; ++i) { unsigned long long o = swave[i]; if (o > w) w = o; }
            swin = w;
        }
        __syncthreads();
        unsigned long long w = swin;
        int wtid = (int)(0xFFFFFFFFu - (unsigned)(w & 0xFFFFFFFFull));
        unsigned vbits = (unsigned)(w >> 32);
        if (t == wtid) {
            int sel = 0; float wx = 0.f, wy = 0.f, wz = 0.f;
#pragma unroll
            for (int i = 15; i >= 0; --i) {  // descending so the FINAL hit is the smallest i
                if (__float_as_uint(dist[i]) == vbits) { sel = i; wx = px[i]; wy = py[i]; wz = pz[i]; }
            }
            sfar = t * 16 + sel;
            sc[0] = wx; sc[1] = wy; sc[2] = wz;
        }
        __syncthreads();
    }
}

// =====================================================================
// K2: exact 32-NN, wave per centroid (8192 waves). R1's PASSING
// decision semantics: key = fmaxf(d2,0) (d2 = (sa+sb) - 2*dot, exact
// fp32 chain), strict-< insert with idx tie-break. Wave structure:
// lane processes a 256-pt stripe into per-lane sorted-32; tau prune
// (wave-min of lanes' key[31] -- provably safe upper bound on global
// 32nd); final exact merge = 32 rounds of u64 wave-argmin + pop.
// Emits nn_idx + nn_key (d2 keys) like R1.
// =====================================================================
__global__ __launch_bounds__(256, 4) void knn_kernel(const float4* __restrict__ pts4,
                                                     const int* __restrict__ fps_idx,
                                                     float* __restrict__ newxyz,
                                                     int* __restrict__ nn_idx,
                                                     float* __restrict__ nn_key) {
    const int lane = threadIdx.x & 63;
    const int g    = blockIdx.x * 4 + (threadIdx.x >> 6);   // centroid 0..8191
    const int b    = g >> 12;
    const float4* P = pts4 + (size_t)b * NPTS;

    const int far = fps_idx[g];
    const float4 C = P[far];
    if (lane == 0) {
        newxyz[g * 3 + 0] = C.x;
        newxyz[g * 3 + 1] = C.y;
        newxyz[g * 3 + 2] = C.z;
    }
    const float sa = C.w;   // same exact formula as R1's inline sum

    float key[KGN]; int nid[KGN];
#pragma unroll
    for (int s = 0; s < KGN; ++s) { key[s] = FLT_MAX; nid[s] = 0x7FFFFFFF; }
    float tau = FLT_MAX;

    for (int c0 = 0; c0 < NPTS; c0 += 1024) {
#pragma unroll 4
        for (int kk = 0; kk < 16; ++kk) {
            const int j = c0 + kk * 64 + lane;
            const float4 Q = P[j];
            const float dot = exadd(exadd(exmul(C.x, Q.x), exmul(C.y, Q.y)), exmul(C.z, Q.z));
            const float d2  = exsub(exadd(sa, Q.w), exadd(dot, dot));
            const float dk  = fmaxf(d2, 0.0f);           // R1's ranking key
            const bool pass = ((dk < key[KGN-1]) || (dk == key[KGN-1] && j < nid[KGN-1]))
                              && (dk <= tau);
            if (pass) {
                float ck = dk; int cj = j;
#pragma unroll
                for (int s = 0; s < KGN; ++s) {
                    const bool sw = (ck < key[s]) || (ck == key[s] && cj < nid[s]);
                    const float tk = key[s]; const int tj = nid[s];
                    key[s] = sw ? ck : tk;  nid[s] = sw ? cj : tj;
                    ck     = sw ? tk : ck;  cj     = sw ? tj : cj;
                }
            }
        }
        float t31 = key[KGN - 1];
#pragma unroll
        for (int off = 1; off < 64; off <<= 1) t31 = fminf(t31, __shfl_xor(t31, off));
        tau = t31;
    }

    // ---- exact cross-lane merge: 32 rounds of wave-argmin + pop ----
    float okey = 0.0f; int oidx = 0;
    for (int r = 0; r < KGN; ++r) {
        const unsigned long long pk =
            ((unsigned long long)__float_as_uint(key[0]) << 32) | (unsigned)nid[0];
        unsigned long long mn = pk;
#pragma unroll
        for (int off = 1; off < 64; off <<= 1) {
            unsigned long long o = __shfl_xor(mn, off);
            mn = (o < mn) ? o : mn;
        }
        if (lane == r) {
            okey = __uint_as_float((unsigned)(mn >> 32));
            oidx = (int)(mn & 0xFFFFFFFFull);
        }
        if (pk == mn) {      // unique owner (idx unique); pop head
#pragma unroll
            for (int s = 0; s < KGN - 1; ++s) { key[s] = key[s + 1]; nid[s] = nid[s + 1]; }
            key[KGN - 1] = FLT_MAX; nid[KGN - 1] = 0x7FFFFFFF;
        }
    }
    if (lane < KGN) {
        nn_idx[(size_t)g * KGN + lane] = oidx;
        nn_key[(size_t)g * KGN + lane] = okey;
    }
}

// =====================================================================
// K3: shared MLP 3->32->32->64 (+BN affine +ReLU), radius mask via
// sqrtf(nn_key) <= 0.8 (R1 verbatim), max over 32 neighbors.
// =====================================================================
__global__ __launch_bounds__(256) void mlp_kernel(const float* __restrict__ xyz,
                                                  const float* __restrict__ w1, const float* __restrict__ s1, const float* __restrict__ b1,
                                                  const float* __restrict__ w2, const float* __restrict__ s2, const float* __restrict__ b2,
                                                  const float* __restrict__ w3, const float* __restrict__ s3, const float* __restrict__ b3,
                                                  const float* __restrict__ newxyz,
                                                  const int* __restrict__ nn_idx,
                                                  const float* __restrict__ nn_key,
                                                  float* __restrict__ FLout) {
    __shared__ float W1[96], S1[32], B1[32];
    __shared__ float W2[1024], S2[32], B2[32];
    __shared__ float W3[2048], S3[64], B3[64];
    const int tid = threadIdx.x;
    for (int i = tid; i < 96; i += 256)   W1[i] = w1[i];
    for (int i = tid; i < 32; i += 256) { S1[i] = s1[i]; B1[i] = b1[i]; S2[i] = s2[i]; B2[i] = b2[i]; }
    for (int i = tid; i < 1024; i += 256) W2[i] = w2[i];
    for (int i = tid; i < 2048; i += 256) W3[i] = w3[i];
    for (int i = tid; i < 64; i += 256) { S3[i] = s3[i]; B3[i] = b3[i]; }
    __syncthreads();

    const int n  = tid & 31;
    const int g  = blockIdx.x * 8 + (tid >> 5);   // centroid 0..8191
    const int b  = g >> 12;
    const size_t base = (size_t)g * KGN + n;
    const int   nj = nn_idx[base];
    const float nk = nn_key[base];

    const float* X = xyz + (size_t)b * NPTS * 3;
    const float gx = X[nj * 3 + 0] - newxyz[g * 3 + 0];
    const float gy = X[nj * 3 + 1] - newxyz[g * 3 + 1];
    const float gz = X[nj * 3 + 2] - newxyz[g * 3 + 2];

    float h1[32];
#pragma unroll
    for (int o = 0; o < 32; ++o) {
        float a = gx * W1[o * 3 + 0] + gy * W1[o * 3 + 1] + gz * W1[o * 3 + 2];
        h1[o] = fmaxf(a * S1[o] + B1[o], 0.0f);
    }
    float h2[32];
#pragma unroll
    for (int o = 0; o < 32; ++o) {
        float a = 0.0f;
#pragma unroll
        for (int k = 0; k < 32; ++k) a += h1[k] * W2[o * 32 + k];
        h2[o] = fmaxf(a * S2[o] + B2[o], 0.0f);
    }
    const bool valid = (sqrtf(nk) <= 0.8f);   // R1's exact mask

    for (int o = 0; o < 64; ++o) {
        float a = 0.0f;
#pragma unroll
        for (int k = 0; k < 32; ++k) a += h2[k] * W3[o * 32 + k];
        float v = fmaxf(a * S3[o] + B3[o], 0.0f);
        v = valid ? v : -INFINITY;
#pragma unroll
        for (int off = 1; off < 32; off <<= 1) v = fmaxf(v, __shfl_xor(v, off));
        if (n == (o & 31)) FLout[(size_t)g * CLN + o] = v;
    }
}

// =====================================================================
// K4: DAM fusion (R1 verbatim). Wave per centroid, lane = channel.
// LDS-transposed 64x64 weights for conflict-free per-lane reads.
// =====================================================================
__global__ __launch_bounds__(256) void fuse_kernel(const float* __restrict__ pts_cam,
                                                   const float* __restrict__ FIn,
                                                   const float* __restrict__ tw1, const float* __restrict__ tb1,
                                                   const float* __restrict__ tw2, const float* __restrict__ tb2,
                                                   const float* __restrict__ tw3, const float* __restrict__ tb3,
                                                   const float* __restrict__ gw_raw, const float* __restrict__ gb_raw,
                                                   const float* __restrict__ gw_img, const float* __restrict__ gb_img,
                                                   const float* __restrict__ gw_lid, const float* __restrict__ gb_lid,
                                                   const float* __restrict__ uw, const float* __restrict__ ub,
                                                   const float* __restrict__ vw, const float* __restrict__ vb,
                                                   const int* __restrict__ fps_idx,
                                                   const float* __restrict__ newxyz,
                                                   const float* __restrict__ FLin,
                                                   float* __restrict__ out) {
    __shared__ float WIm[4096], WLi[4096], WT2[4096];
    const int tid = threadIdx.x;
    for (int i = tid; i < 4096; i += 256) {
        int c = i >> 6, k = i & 63;          // weight[c][k] -> transposed [k][c]
        WIm[k * 64 + c] = gw_img[i];
        WLi[k * 64 + c] = gw_lid[i];
        WT2[k * 64 + c] = tw2[i];
    }
    __syncthreads();

    const int lane = tid & 63;
    const int g    = blockIdx.x * 4 + (tid >> 6);   // centroid 0..8191
    const int b    = g >> 12;
    const int m    = g & (MPTS - 1);
    const int far  = fps_idx[g];

    const float fi_in = FIn[((size_t)(b * CIN + lane)) * NPTS + far];
    const float fl_in = FLin[(size_t)g * CLN + lane];
    const float nx = newxyz[g * 3 + 0], ny = newxyz[g * 3 + 1], nz = newxyz[g * 3 + 2];

    float fr = fmaxf(nx * gw_raw[lane * 3 + 0] + ny * gw_raw[lane * 3 + 1] +
                     nz * gw_raw[lane * 3 + 2] + gb_raw[lane], 0.0f);

    float ai = gb_img[lane], al = gb_lid[lane];
#pragma unroll 8
    for (int k = 0; k < 64; ++k) {
        float vi = __shfl(fi_in, k);
        float vl = __shfl(fl_in, k);
        ai += vi * WIm[k * 64 + lane];
        al += vl * WLi[k * 64 + lane];
    }
    const float s = tanhf(fr + fmaxf(ai, 0.0f) + fmaxf(al, 0.0f));

    // AdaptiveThresholdNet on constant density
    const float dens = (float)(64.0 / (4.0 / 3.0 * 3.14159 * 1.0));
    float t1 = fmaxf(dens * tw1[lane] + tb1[lane], 0.0f);
    float a2 = tb2[lane];
#pragma unroll 8
    for (int k = 0; k < 64; ++k) a2 += __shfl(t1, k) * WT2[k * 64 + lane];
    float t2 = fmaxf(a2, 0.0f);
    float a3 = wave_sum64(t2 * tw3[lane]) + tb3[0];
    float thr = 20.0f + 40.0f * (1.0f / (1.0f + expf(-a3)));

    float aI = wave_sum64(s * uw[lane]) + ub[0];
    float aL = wave_sum64(s * vw[lane]) + vb[0];
    float wIv = 1.0f / (1.0f + expf(-aI));
    float wLv = 1.0f / (1.0f + expf(-aL));

    const float z = pts_cam[((size_t)b * NPTS + far) * 3 + 2];
    const bool near = (z <= thr);

    const size_t o1 = ((size_t)(b * 128 + lane)) * MPTS + m;
    out[o1]                       = near ? fl_in        : fi_in;
    out[o1 + (size_t)64 * MPTS]   = near ? fi_in * wIv  : fl_in * wLv;
}

// =====================================================================
extern "C" void kernel_launch(void* const* d_in, const int* in_sizes, int n_in,
                              void* d_out, int out_size, void* d_ws, size_t ws_size,
                              hipStream_t stream) {
    const float* xyz     = (const float*)d_in[0];
    const float* pts_cam = (const float*)d_in[1];
    const float* FI      = (const float*)d_in[2];
    const float* w1 = (const float*)d_in[3];
    const float* s1 = (const float*)d_in[4];
    const float* b1 = (const float*)d_in[5];
    const float* w2 = (const float*)d_in[6];
    const float* s2 = (const float*)d_in[7];
    const float* b2 = (const float*)d_in[8];
    const float* w3 = (const float*)d_in[9];
    const float* s3 = (const float*)d_in[10];
    const float* b3 = (const float*)d_in[11];
    const float* tw1 = (const float*)d_in[12];
    const float* tb1 = (const float*)d_in[13];
    const float* tw2 = (const float*)d_in[14];
    const float* tb2 = (const float*)d_in[15];
    const float* tw3 = (const float*)d_in[16];
    const float* tb3 = (const float*)d_in[17];
    const float* gw_raw = (const float*)d_in[18];
    const float* gb_raw = (const float*)d_in[19];
    const float* gw_img = (const float*)d_in[20];
    const float* gb_img = (const float*)d_in[21];
    const float* gw_lid = (const float*)d_in[22];
    const float* gb_lid = (const float*)d_in[23];
    const float* uw = (const float*)d_in[24];
    const float* ub = (const float*)d_in[25];
    const float* vw = (const float*)d_in[26];
    const float* vb = (const float*)d_in[27];
    float* out = (float*)d_out;

    // workspace layout (bytes) — total 4,325,376 (== R1's proven footprint).
    // pts4 is dead after knn; FL (written by mlp, later) aliases its region.
    char* ws = (char*)d_ws;
    int*    ws_idx    = (int*)   (ws + 0);         // 8192 ints    (32 KB)
    float*  ws_newxyz = (float*) (ws + 32768);     // 24576 f      (96 KB)  -> 131072
    float4* ws_pts4   = (float4*)(ws + 131072);    // 32768 float4 (512 KB) -> 655360 [dead after knn]
    float*  ws_FL     = (float*) (ws + 131072);    // 524288 f     (2 MB)   -> 2228224 [aliases pts4]
    int*    ws_nnidx  = (int*)   (ws + 2228224);   // 262144 ints  (1 MB)   -> 3276800
    float*  ws_nnkey  = (float*) (ws + 3276800);   // 262144 f     (1 MB)   -> 4325376
    (void)ws_size; (void)in_sizes; (void)n_in; (void)out_size;

    prep_kernel<<<(BN * NPTS) / 256, 256, 0, stream>>>(xyz, ws_pts4);
    fps_kernel<<<BN, 1024, 0, stream>>>(ws_pts4, ws_idx);
    knn_kernel<<<2048, 256, 0, stream>>>(ws_pts4, ws_idx, ws_newxyz, ws_nnidx, ws_nnkey);
    mlp_kernel<<<1024, 256, 0, stream>>>(xyz, w1, s1, b1, w2, s2, b2, w3, s3, b3,
                                         ws_newxyz, ws_nnidx, ws_nnkey, ws_FL);
    fuse_kernel<<<2048, 256, 0, stream>>>(pts_cam, FI, tw1, tb1, tw2, tb2, tw3, tb3,
                                          gw_raw, gb_raw, gw_img, gb_img, gw_lid, gb_lid,
                                          uw, ub, vw, vb, ws_idx, ws_newxyz, ws_FL, out);
}

// Round 4
// 7307.784 us; speedup vs baseline: 2.6209x; 2.6209x over previous
//
#include <hip/hip_runtime.h>
#include <math.h>
#include <float.h>

#define BN   2
#define NPTS 16384
#define MPTS 4096
#define KGN  32
#define CIN  64
#define CLN  64

// ---------- exact fp32 helpers (no FMA contraction; must match np fp32) ----------
__device__ __forceinline__ float exadd(float a, float b) {
#pragma clang fp contract(off)
    float r = a + b; return r;
}
__device__ __forceinline__ float exsub(float a, float b) {
#pragma clang fp contract(off)
    float r = a - b; return r;
}
__device__ __forceinline__ float exmul(float a, float b) {
#pragma clang fp contract(off)
    float r = a * b; return r;
}

__device__ __forceinline__ float wave_sum64(float v) {
#pragma unroll
    for (int off = 1; off < 64; off <<= 1) v += __shfl_xor(v, off);
    return v;
}

// =====================================================================
// K0: pack points as float4(x, y, z, ||p||^2) once. sb order matches
// jnp.sum(b*b,-1): ((x*x + y*y) + z*z), contract off. Values verbatim.
// =====================================================================
__global__ __launch_bounds__(256) void prep_kernel(const float* __restrict__ xyz,
                                                   float4* __restrict__ pts4) {
    const int i = blockIdx.x * 256 + threadIdx.x;   // 0 .. BN*NPTS-1
    const float x = xyz[3 * i + 0];
    const float y = xyz[3 * i + 1];
    const float z = xyz[3 * i + 2];
    const float sb = exadd(exadd(exmul(x, x), exmul(y, y)), exmul(z, z));
    pts4[i] = make_float4(x, y, z, sb);
}

// =====================================================================
// K1: FPS — R3's PASSING kernel, arithmetic/reduction/tie-break verbatim.
// Changes (value-neutral, codegen only):
//   * amdgpu_waves_per_eu(4,4): 16-wave block = exactly 4 waves/EU, so
//     max=4 is truthful; raises VGPR budget to 128 and stops the
//     scheduler from targeting 8 waves/EU (the 64-VGPR cap that caused
//     per-iteration re-loads of px/py/pz from L2 — R3: 16.8K cyc/iter).
//   * asm pin on px/py/pz after load: forbids load-rematerialization.
// =====================================================================
__global__ __attribute__((amdgpu_waves_per_eu(4, 4)))
__launch_bounds__(1024) void fps_kernel(const float4* __restrict__ P4,
                                        int* __restrict__ out_idx) {
    const int b = blockIdx.x;
    const int t = threadIdx.x;
    const float4* P = P4 + (size_t)b * NPTS;

    float px[16], py[16], pz[16], dist[16];
#pragma unroll
    for (int i = 0; i < 16; ++i) {
        float4 a = P[t * 16 + i];
        px[i] = a.x;
        py[i] = a.y;
        pz[i] = a.z;
        dist[i] = 1e10f;
    }
#pragma unroll
    for (int i = 0; i < 16; ++i) {
        asm volatile("" : "+v"(px[i]), "+v"(py[i]), "+v"(pz[i]));
    }

    __shared__ float sc[3];
    __shared__ int   sfar;
    __shared__ unsigned long long swave[16];
    __shared__ unsigned long long swin;

    if (t == 0) { sc[0] = px[0]; sc[1] = py[0]; sc[2] = pz[0]; sfar = 0; }
    __syncthreads();

    for (int m = 0; m < MPTS; ++m) {
        float cx = sc[0], cy = sc[1], cz = sc[2];
        if (t == 0) out_idx[b * MPTS + m] = sfar;

        float lmax = -1.0f;
#pragma unroll
        for (int i = 0; i < 16; ++i) {
            float dx = exsub(px[i], cx);
            float dy = exsub(py[i], cy);
            float dz = exsub(pz[i], cz);
            float d  = exadd(exadd(exmul(dx, dx), exmul(dy, dy)), exmul(dz, dz));
            float nd = fminf(dist[i], d);
            dist[i] = nd;
            lmax = fmaxf(lmax, nd);
        }
        // pack: value bits in hi 32 (dist >= 0 so monotone), ~tid in lo 32 -> max picks min tid on ties
        unsigned long long pk =
            ((unsigned long long)__float_as_uint(lmax) << 32) |
            (unsigned long long)(0xFFFFFFFFu - (unsigned)t);
#pragma unroll
        for (int off = 32; off > 0; off >>= 1) {
            unsigned long long o = __shfl_xor(pk, off);
            pk = (o > pk) ? o : pk;
        }
        if ((t & 63) == 0) swave[t >> 6] = pk;
        __syncthreads();
        if (t == 0) {
            unsigned long long w = swave[0];
#pragma unroll
            for (int i = 1; i < 16; ++i) { unsigned long long o = swave[i]; if (o > w) w = o; }
            swin = w;
        }
        __syncthreads();
        unsigned long long w = swin;
        int wtid = (int)(0xFFFFFFFFu - (unsigned)(w & 0xFFFFFFFFull));
        unsigned vbits = (unsigned)(w >> 32);
        if (t == wtid) {
            int sel = 0; float wx = 0.f, wy = 0.f, wz = 0.f;
#pragma unroll
            for (int i = 15; i >= 0; --i) {  // descending so the FINAL hit is the smallest i
                if (__float_as_uint(dist[i]) == vbits) { sel = i; wx = px[i]; wy = py[i]; wz = pz[i]; }
            }
            sfar = t * 16 + sel;
            sc[0] = wx; sc[1] = wy; sc[2] = wz;
        }
        __syncthreads();
    }
}

// =====================================================================
// K2: exact 32-NN, wave per centroid, NO per-lane arrays (R3 spilled
// its key[32]/nid[32] to scratch: 18.9 GB FETCH / 12.6 GB WRITE).
// Wave-wide sorted top-32 lives in ONE (key,idx) register pair per
// lane (lanes 0..31, ascending (key,idx) lex). Candidates found via
// ballot; each inserted exactly: p = popc(ballot(lex-less)), shift
// lanes >= p up by one, lane p takes the candidate.
// Exactness: selection by (key,idx) lex = lax.top_k stable set; insert
// order irrelevant (final content = top-32 of union). Keys use R3's
// exact chain: d2 = (sa+sb) - 2*dot, key = fmaxf(d2,0).
// Radius pre-filter sqrtf(dk)<=0.8f is set-equivalent: the radius set
// is down-closed in key order, so top32(all) ∩ radius == top32(radius)
// (proof: if >=32 in-radius, the 32 global-nearest all have key <= the
// in-radius 32nd key, hence in-radius; else all in-radius points are
// among the global top-32). Sentinels (FLT_MAX, idx 0) fail the mask
// in mlp and idx 0 is a safe gather.
// =====================================================================
__global__ __launch_bounds__(256) void knn_kernel(const float4* __restrict__ pts4,
                                                  const int* __restrict__ fps_idx,
                                                  float* __restrict__ newxyz,
                                                  int* __restrict__ nn_idx,
                                                  float* __restrict__ nn_key) {
    const int lane = threadIdx.x & 63;
    const int g    = blockIdx.x * 4 + (threadIdx.x >> 6);   // centroid 0..8191
    const int b    = g >> 12;
    const float4* P = pts4 + (size_t)b * NPTS;

    const int far = fps_idx[g];
    const float4 C = P[far];
    if (lane == 0) {
        newxyz[g * 3 + 0] = C.x;
        newxyz[g * 3 + 1] = C.y;
        newxyz[g * 3 + 2] = C.z;
    }
    const float sa = C.w;

    float skey = FLT_MAX;   // lanes 0..31: sorted entries; lanes 32..63: inert
    int   sidx = 0;

    for (int it = 0; it < NPTS / 64; ++it) {
        const int j = it * 64 + lane;
        const float4 Q = P[j];
        const float dot = exadd(exadd(exmul(C.x, Q.x), exmul(C.y, Q.y)), exmul(C.z, Q.z));
        const float d2  = exsub(exadd(sa, Q.w), exadd(dot, dot));
        const float dk  = fmaxf(d2, 0.0f);
        // current 32nd-best (tau) from lane 31 — stale within the iteration is
        // fine: the insert itself recomputes the exact position.
        const float tk = __shfl(skey, 31);
        const int   ti = __shfl(sidx, 31);
        const bool pass = (sqrtf(dk) <= 0.8f) &&
                          ((dk < tk) || (dk == tk && j < ti));
        unsigned long long mask = __ballot(pass);
        while (mask) {
            const int src = __ffsll(mask) - 1;
            mask &= mask - 1;
            const float ck = __shfl(dk, src);
            const int   cj = it * 64 + src;
            const bool less = (skey < ck) || (skey == ck && sidx < cj);
            const int p = __popcll(__ballot(less));   // wave-uniform rank
            if (p < 32) {                              // wave-uniform branch
                const float upk = __shfl_up(skey, 1);
                const int   upi = __shfl_up(sidx, 1);
                if (lane < 32) {
                    if (lane == p)     { skey = ck;  sidx = cj; }
                    else if (lane > p) { skey = upk; sidx = upi; }
                }
            }
        }
    }
    if (lane < KGN) {
        nn_idx[(size_t)g * KGN + lane] = sidx;
        nn_key[(size_t)g * KGN + lane] = skey;
    }
}

// =====================================================================
// K3: shared MLP 3->32->32->64 (+BN affine +ReLU), radius mask via
// sqrtf(nn_key) <= 0.8 (R3 verbatim), max over 32 neighbors.
// waves_per_eu(4,4): h1+h2 = 64 live floats — same spill class as knn;
// raise budget to 128 (value-neutral).
// =====================================================================
__global__ __attribute__((amdgpu_waves_per_eu(4, 4)))
__launch_bounds__(256) void mlp_kernel(const float* __restrict__ xyz,
                                       const float* __restrict__ w1, const float* __restrict__ s1, const float* __restrict__ b1,
                                       const float* __restrict__ w2, const float* __restrict__ s2, const float* __restrict__ b2,
                                       const float* __restrict__ w3, const float* __restrict__ s3, const float* __restrict__ b3,
                                       const float* __restrict__ newxyz,
                                       const int* __restrict__ nn_idx,
                                       const float* __restrict__ nn_key,
                                       float* __restrict__ FLout) {
    __shared__ float W1[96], S1[32], B1[32];
    __shared__ float W2[1024], S2[32], B2[32];
    __shared__ float W3[2048], S3[64], B3[64];
    const int tid = threadIdx.x;
    for (int i = tid; i < 96; i += 256)   W1[i] = w1[i];
    for (int i = tid; i < 32; i += 256) { S1[i] = s1[i]; B1[i] = b1[i]; S2[i] = s2[i]; B2[i] = b2[i]; }
    for (int i = tid; i < 1024; i += 256) W2[i] = w2[i];
    for (int i = tid; i < 2048; i += 256) W3[i] = w3[i];
    for (int i = tid; i < 64; i += 256) { S3[i] = s3[i]; B3[i] = b3[i]; }
    __syncthreads();

    const int n  = tid & 31;
    const int g  = blockIdx.x * 8 + (tid >> 5);   // centroid 0..8191
    const int b  = g >> 12;
    const size_t base = (size_t)g * KGN + n;
    const int   nj = nn_idx[base];
    const float nk = nn_key[base];

    const float* X = xyz + (size_t)b * NPTS * 3;
    const float gx = X[nj * 3 + 0] - newxyz[g * 3 + 0];
    const float gy = X[nj * 3 + 1] - newxyz[g * 3 + 1];
    const float gz = X[nj * 3 + 2] - newxyz[g * 3 + 2];

    float h1[32];
#pragma unroll
    for (int o = 0; o < 32; ++o) {
        float a = gx * W1[o * 3 + 0] + gy * W1[o * 3 + 1] + gz * W1[o * 3 + 2];
        h1[o] = fmaxf(a * S1[o] + B1[o], 0.0f);
    }
    float h2[32];
#pragma unroll
    for (int o = 0; o < 32; ++o) {
        float a = 0.0f;
#pragma unroll
        for (int k = 0; k < 32; ++k) a += h1[k] * W2[o * 32 + k];
        h2[o] = fmaxf(a * S2[o] + B2[o], 0.0f);
    }
    const bool valid = (sqrtf(nk) <= 0.8f);   // exact mask (sentinel FLT_MAX -> false)

    for (int o = 0; o < 64; ++o) {
        float a = 0.0f;
#pragma unroll
        for (int k = 0; k < 32; ++k) a += h2[k] * W3[o * 32 + k];
        float v = fmaxf(a * S3[o] + B3[o], 0.0f);
        v = valid ? v : -INFINITY;
#pragma unroll
        for (int off = 1; off < 32; off <<= 1) v = fmaxf(v, __shfl_xor(v, off));
        if (n == (o & 31)) FLout[(size_t)g * CLN + o] = v;
    }
}

// =====================================================================
// K4: DAM fusion (R3 verbatim). Wave per centroid, lane = channel.
// LDS-transposed 64x64 weights for conflict-free per-lane reads.
// =====================================================================
__global__ __launch_bounds__(256) void fuse_kernel(const float* __restrict__ pts_cam,
                                                   const float* __restrict__ FIn,
                                                   const float* __restrict__ tw1, const float* __restrict__ tb1,
                                                   const float* __restrict__ tw2, const float* __restrict__ tb2,
                                                   const float* __restrict__ tw3, const float* __restrict__ tb3,
                                                   const float* __restrict__ gw_raw, const float* __restrict__ gb_raw,
                                                   const float* __restrict__ gw_img, const float* __restrict__ gb_img,
                                                   const float* __restrict__ gw_lid, const float* __restrict__ gb_lid,
                                                   const float* __restrict__ uw, const float* __restrict__ ub,
                                                   const float* __restrict__ vw, const float* __restrict__ vb,
                                                   const int* __restrict__ fps_idx,
                                                   const float* __restrict__ newxyz,
                                                   const float* __restrict__ FLin,
                                                   float* __restrict__ out) {
    __shared__ float WIm[4096], WLi[4096], WT2[4096];
    const int tid = threadIdx.x;
    for (int i = tid; i < 4096; i += 256) {
        int c = i >> 6, k = i & 63;          // weight[c][k] -> transposed [k][c]
        WIm[k * 64 + c] = gw_img[i];
        WLi[k * 64 + c] = gw_lid[i];
        WT2[k * 64 + c] = tw2[i];
    }
    __syncthreads();

    const int lane = tid & 63;
    const int g    = blockIdx.x * 4 + (tid >> 6);   // centroid 0..8191
    const int b    = g >> 12;
    const int m    = g & (MPTS - 1);
    const int far  = fps_idx[g];

    const float fi_in = FIn[((size_t)(b * CIN + lane)) * NPTS + far];
    const float fl_in = FLin[(size_t)g * CLN + lane];
    const float nx = newxyz[g * 3 + 0], ny = newxyz[g * 3 + 1], nz = newxyz[g * 3 + 2];

    float fr = fmaxf(nx * gw_raw[lane * 3 + 0] + ny * gw_raw[lane * 3 + 1] +
                     nz * gw_raw[lane * 3 + 2] + gb_raw[lane], 0.0f);

    float ai = gb_img[lane], al = gb_lid[lane];
#pragma unroll 8
    for (int k = 0; k < 64; ++k) {
        float vi = __shfl(fi_in, k);
        float vl = __shfl(fl_in, k);
        ai += vi * WIm[k * 64 + lane];
        al += vl * WLi[k * 64 + lane];
    }
    const float s = tanhf(fr + fmaxf(ai, 0.0f) + fmaxf(al, 0.0f));

    // AdaptiveThresholdNet on constant density
    const float dens = (float)(64.0 / (4.0 / 3.0 * 3.14159 * 1.0));
    float t1 = fmaxf(dens * tw1[lane] + tb1[lane], 0.0f);
    float a2 = tb2[lane];
#pragma unroll 8
    for (int k = 0; k < 64; ++k) a2 += __shfl(t1, k) * WT2[k * 64 + lane];
    float t2 = fmaxf(a2, 0.0f);
    float a3 = wave_sum64(t2 * tw3[lane]) + tb3[0];
    float thr = 20.0f + 40.0f * (1.0f / (1.0f + expf(-a3)));

    float aI = wave_sum64(s * uw[lane]) + ub[0];
    float aL = wave_sum64(s * vw[lane]) + vb[0];
    float wIv = 1.0f / (1.0f + expf(-aI));
    float wLv = 1.0f / (1.0f + expf(-aL));

    const float z = pts_cam[((size_t)b * NPTS + far) * 3 + 2];
    const bool near = (z <= thr);

    const size_t o1 = ((size_t)(b * 128 + lane)) * MPTS + m;
    out[o1]                       = near ? fl_in        : fi_in;
    out[o1 + (size_t)64 * MPTS]   = near ? fi_in * wIv  : fl_in * wLv;
}

// =====================================================================
extern "C" void kernel_launch(void* const* d_in, const int* in_sizes, int n_in,
                              void* d_out, int out_size, void* d_ws, size_t ws_size,
                              hipStream_t stream) {
    const float* xyz     = (const float*)d_in[0];
    const float* pts_cam = (const float*)d_in[1];
    const float* FI      = (const float*)d_in[2];
    const float* w1 = (const float*)d_in[3];
    const float* s1 = (const float*)d_in[4];
    const float* b1 = (const float*)d_in[5];
    const float* w2 = (const float*)d_in[6];
    const float* s2 = (const float*)d_in[7];
    const float* b2 = (const float*)d_in[8];
    const float* w3 = (const float*)d_in[9];
    const float* s3 = (const float*)d_in[10];
    const float* b3 = (const float*)d_in[11];
    const float* tw1 = (const float*)d_in[12];
    const float* tb1 = (const float*)d_in[13];
    const float* tw2 = (const float*)d_in[14];
    const float* tb2 = (const float*)d_in[15];
    const float* tw3 = (const float*)d_in[16];
    const float* tb3 = (const float*)d_in[17];
    const float* gw_raw = (const float*)d_in[18];
    const float* gb_raw = (const float*)d_in[19];
    const float* gw_img = (const float*)d_in[20];
    const float* gb_img = (const float*)d_in[21];
    const float* gw_lid = (const float*)d_in[22];
    const float* gb_lid = (const float*)d_in[23];
    const float* uw = (const float*)d_in[24];
    const float* ub = (const float*)d_in[25];
    const float* vw = (const float*)d_in[26];
    const float* vb = (const float*)d_in[27];
    float* out = (float*)d_out;

    // workspace layout (bytes) — total 4,325,376.
    // pts4 is dead after knn; FL (written by mlp, later) aliases its region.
    char* ws = (char*)d_ws;
    int*    ws_idx    = (int*)   (ws + 0);         // 8192 ints    (32 KB)
    float*  ws_newxyz = (float*) (ws + 32768);     // 24576 f      (96 KB)  -> 131072
    float4* ws_pts4   = (float4*)(ws + 131072);    // 32768 float4 (512 KB) -> 655360 [dead after knn]
    float*  ws_FL     = (float*) (ws + 131072);    // 524288 f     (2 MB)   -> 2228224 [aliases pts4]
    int*    ws_nnidx  = (int*)   (ws + 2228224);   // 262144 ints  (1 MB)   -> 3276800
    float*  ws_nnkey  = (float*) (ws + 3276800);   // 262144 f     (1 MB)   -> 4325376
    (void)ws_size; (void)in_sizes; (void)n_in; (void)out_size;

    prep_kernel<<<(BN * NPTS) / 256, 256, 0, stream>>>(xyz, ws_pts4);
    fps_kernel<<<BN, 1024, 0, stream>>>(ws_pts4, ws_idx);
    knn_kernel<<<2048, 256, 0, stream>>>(ws_pts4, ws_idx, ws_newxyz, ws_nnidx, ws_nnkey);
    mlp_kernel<<<1024, 256, 0, stream>>>(xyz, w1, s1, b1, w2, s2, b2, w3, s3, b3,
                                         ws_newxyz, ws_nnidx, ws_nnkey, ws_FL);
    fuse_kernel<<<2048, 256, 0, stream>>>(pts_cam, FI, tw1, tb1, tw2, tb2, tw3, tb3,
                                          gw_raw, gb_raw, gw_img, gb_img, gw_lid, gb_lid,
                                          uw, ub, vw, vb, ws_idx, ws_newxyz, ws_FL, out);
}